// Round 1
// 518.660 us; speedup vs baseline: 1.0223x; 1.0223x over previous
//
#include <hip/hip_runtime.h>
#include <cstdint>

#define B_N 32
#define C_N 192
#define W_N 56
#define HW_N 3136
#define CO_N 384
#define K_N 384
#define M_N 100352   // B_N * HW_N

typedef unsigned short u16;
typedef unsigned int u32;
typedef __attribute__((ext_vector_type(8))) short short8;
typedef __attribute__((ext_vector_type(4))) float floatx4;

__device__ __forceinline__ u16 bf16rne(float f) {
  union { float f; u32 u; } v; v.f = f;
  u32 r = (v.u + 0x7FFFu + ((v.u >> 16) & 1u)) >> 16;
  return (u16)r;
}

// ---- direct global->LDS staging (16B/lane). lbase must be wave-uniform. ----
__device__ __forceinline__ void stage16(const void* g, void* lbase, int lane) {
#if __has_builtin(__builtin_amdgcn_global_load_lds)
  __builtin_amdgcn_global_load_lds(
      (const __attribute__((address_space(1))) void*)(uintptr_t)g,
      (__attribute__((address_space(3))) void*)(u32)(uintptr_t)lbase,
      16, 0, 0);
#else
  *(uint4*)((char*)lbase + lane * 16) = *(const uint4*)g;
#endif
}

// ============ K0: fold BN consts, convert W to bf16 ============
__global__ __launch_bounds__(256) void prep_consts(
    const float* __restrict__ Wc, const float* __restrict__ bconv,
    const float* __restrict__ gamma, const float* __restrict__ beta,
    const float* __restrict__ rmean, const float* __restrict__ rvar,
    u16* __restrict__ Wbf, float* __restrict__ alphaV, float* __restrict__ betaV) {
  int idx = blockIdx.x * 256 + threadIdx.x;
  if (idx < CO_N * K_N) Wbf[idx] = bf16rne(Wc[idx]);
  if (idx < CO_N) {
    float s = gamma[idx] * rsqrtf(rvar[idx] + 1e-5f);
    alphaV[idx] = s;
    betaV[idx] = bconv[idx] * s + beta[idx] - rmean[idx] * s;
  }
}

// ============ K1: per-(b,c) plane -> xj (bf16) ============
__global__ __launch_bounds__(256) void xj_compute(const float* __restrict__ x,
                                                  u16* __restrict__ XJ) {
  __shared__ float pl[HW_N];
  __shared__ float rmin1[112], rmin2[112], cmin1[112], cmin2[112];
  __shared__ int rarg[112], carg[112];
  int tid = threadIdx.x;
  size_t base = (size_t)blockIdx.x * HW_N;
  const float4* xp4 = (const float4*)(x + base);
  #pragma unroll 1
  for (int i = tid; i < HW_N / 4; i += 256) ((float4*)pl)[i] = xp4[i];
  __syncthreads();
  if (tid < 112) {            // row-direction structure: per (w, parity)
    int ww = tid >> 1, p = tid & 1;
    float m1 = 3e38f, m2 = 3e38f; int am = -1;
    #pragma unroll
    for (int j = 0; j < 28; ++j) {
      int h = p + 2 * j;
      float v = pl[h * W_N + ww];
      if (v < m1) { m2 = m1; m1 = v; am = h; } else if (v < m2) m2 = v;
    }
    rmin1[tid] = m1; rmin2[tid] = m2; rarg[tid] = am;
  } else if (tid < 224) {     // col-direction structure: per (h, parity)
    int t = tid - 112;
    int hh = t >> 1, p = t & 1;
    float m1 = 3e38f, m2 = 3e38f; int am = -1;
    #pragma unroll
    for (int j = 0; j < 28; ++j) {
      int wv = p + 2 * j;
      float v = pl[hh * W_N + wv];
      if (v < m1) { m2 = m1; m1 = v; am = wv; } else if (v < m2) m2 = v;
    }
    cmin1[t] = m1; cmin2[t] = m2; carg[t] = am;
  }
  __syncthreads();
  u16* op = XJ + base;
  #pragma unroll 1
  for (int i4 = tid; i4 < HW_N / 4; i4 += 256) {
    int idx = i4 * 4;
    int h = idx / W_N;
    int w0 = idx - h * W_N;
    ushort4 r;
    u16* rp = &r.x;
    #pragma unroll
    for (int j = 0; j < 4; ++j) {
      int wv = w0 + j;
      float v = pl[idx + j];
      int rt = (wv << 1) | (h & 1);
      float rm = (rarg[rt] == h) ? rmin2[rt] : rmin1[rt];
      int ct = (h << 1) | (wv & 1);
      float cm = (carg[ct] == wv) ? cmin2[ct] : cmin1[ct];
      float xj = v - fminf(rm, cm);
      rp[j] = bf16rne(fmaxf(xj, 0.0f));
    }
    *(ushort4*)(op + idx) = r;
  }
}

// ============ K2: FUSED pack + GEMM + BN + GELU ============
// A-tile is built in LDS directly from x (f32 -> bf16 cvt, pair-pack) and XJ
// (bf16 pair-pack), register-staged, written with the SAME chunk-XOR swizzle
// the fragment reader expects. XC (77 MB write + ~130 MB fetch) and the whole
// pack_xc kernel are eliminated. B (weights) keeps global_load_lds staging.
//
// LDS write mapping: thread (kp = tid&31 channel-pair, pxq = tid>>5 + 8r pixel
// quad) writes u32 (2 packed bf16 of channels 2kp,2kp+1) at
//   As32[px*32 + ((kp>>2)^(px&7))*4 + (kp&3)]
// lanes vary kp -> 32 distinct banks (conflict-free); chunk-XOR identical to
// the previous XC layout so compute_step/frag reads are untouched.

__device__ __forceinline__ void stage_b(const u16* __restrict__ Wbf, u16* Bs,
                                        int n0, int k0, int w, int lrow,
                                        int lchunk, int lane) {
  #pragma unroll
  for (int c = 0; c < 4; ++c) {
    int rowbase = w * 32 + c * 8;
    int row = rowbase + lrow;
    int chunk = lchunk ^ (row & 7);
    stage16(Wbf + (size_t)(n0 + row) * K_N + k0 + chunk * 8,
            Bs + rowbase * 64, lane);
  }
}

__device__ __forceinline__ void compute_step(const u16* As, const u16* Bs,
                                             floatx4 (&acc)[4][4], int wm,
                                             int wn, int l15, int quad) {
  #pragma unroll
  for (int h2 = 0; h2 < 2; ++h2) {
    short8 aF[4], bF[4];
    #pragma unroll
    for (int mi = 0; mi < 4; ++mi) {
      int r = wm * 64 + mi * 16 + l15;
      aF[mi] = *(const short8*)(As + r * 64 + (((h2 * 4 + quad) ^ (r & 7)) * 8));
    }
    #pragma unroll
    for (int ni = 0; ni < 4; ++ni) {
      int r = wn * 64 + ni * 16 + l15;
      bF[ni] = *(const short8*)(Bs + r * 64 + (((h2 * 4 + quad) ^ (r & 7)) * 8));
    }
    #pragma unroll
    for (int mi = 0; mi < 4; ++mi)
      #pragma unroll
      for (int ni = 0; ni < 4; ++ni)
        acc[mi][ni] = __builtin_amdgcn_mfma_f32_16x16x32_bf16(
            aF[mi], bF[ni], acc[mi][ni], 0, 0, 0);
  }
}

__global__ __launch_bounds__(256) void gemm_fused(
    const float* __restrict__ x, const u16* __restrict__ XJ,
    const u16* __restrict__ Wbf,
    const float* __restrict__ alphaV, const float* __restrict__ betaV,
    float* __restrict__ out) {
  __shared__ __align__(16) char smem_raw[32768]; // As 16K + Bs 16K; epilogue 16896 B
  u16* As = (u16*)smem_raw;
  u16* Bs = As + 8192;
  u32* As32 = (u32*)smem_raw;
  float* ep = (float*)smem_raw;
  int tid = threadIdx.x;
  int lane = tid & 63;
  int w = tid >> 6;
  // XCD swizzle: 3 n-blocks sharing one A-slab land on the same XCD (bid%8)
  int bid = blockIdx.x;
  int xcd = bid & 7;
  int slot = bid >> 3;
  int bn = slot % 3;
  int bmg = slot / 3;
  int bm = bmg * 8 + xcd;
  int m0 = bm << 7, n0 = bn << 7;
  int wm = w & 1, wn = w >> 1;
  int l15 = lane & 15, quad = lane >> 4;
  int lrow = lane >> 3;
  int lchunk = lane & 7;

  // ---- A-staging thread mapping ----
  int kp = tid & 31;      // channel pair (2kp, 2kp+1) within 64-k step
  int pxq0 = tid >> 5;    // pixel-quad base (0..7); full range via +8r
  // per-r plane-relative element offsets (128-px tile may straddle a batch
  // plane: 3136/128 = 24.5, so resolve b per pixel-quad)
  u32 offs[4];
  #pragma unroll
  for (int r = 0; r < 4; ++r) {
    int gm = m0 + (pxq0 + 8 * r) * 4;
    int bb = gm / HW_N;
    int pp = gm - bb * HW_N;
    offs[r] = (u32)bb * (u32)(C_N * HW_N) + (u32)pp;
  }

  floatx4 acc[4][4];
  #pragma unroll
  for (int i = 0; i < 4; ++i)
    #pragma unroll
    for (int j = 0; j < 4; ++j) acc[i][j] = (floatx4)0.0f;

  // ---- x0 half: k = 0..191 (channels of x, f32 -> bf16) ----
  #pragma unroll 1
  for (int ko = 0; ko < 3; ++ko) {
    int c0 = ko * 64;
    u32 pk[4][4];
    #pragma unroll
    for (int r = 0; r < 4; ++r) {
      const float* a = x + (size_t)offs[r] + (size_t)(c0 + 2 * kp) * HW_N;
      float4 v0 = *(const float4*)a;
      float4 v1 = *(const float4*)(a + HW_N);
      const float* f0 = &v0.x; const float* f1 = &v1.x;
      #pragma unroll
      for (int j = 0; j < 4; ++j)
        pk[r][j] = (u32)bf16rne(f0[j]) | ((u32)bf16rne(f1[j]) << 16);
    }
    __syncthreads();                 // prev compute done reading As/Bs
    stage_b(Wbf, Bs, n0, c0, w, lrow, lchunk, lane);
    #pragma unroll
    for (int r = 0; r < 4; ++r) {
      int pxb = (pxq0 + 8 * r) * 4;
      #pragma unroll
      for (int j = 0; j < 4; ++j) {
        int px = pxb + j;
        As32[px * 32 + (((kp >> 2) ^ (px & 7)) << 2) + (kp & 3)] = pk[r][j];
      }
    }
    __syncthreads();
    compute_step(As, Bs, acc, wm, wn, l15, quad);
  }

  // ---- xj half: k = 192..383 (channels of XJ, bf16 pair-pack) ----
  #pragma unroll 1
  for (int ko = 0; ko < 3; ++ko) {
    int c0 = ko * 64;
    u32 pk[4][4];
    #pragma unroll
    for (int r = 0; r < 4; ++r) {
      const u16* a = XJ + (size_t)offs[r] + (size_t)(c0 + 2 * kp) * HW_N;
      ushort4 v0 = *(const ushort4*)a;
      ushort4 v1 = *(const ushort4*)(a + HW_N);
      const u16* q0 = &v0.x; const u16* q1 = &v1.x;
      #pragma unroll
      for (int j = 0; j < 4; ++j)
        pk[r][j] = (u32)q0[j] | ((u32)q1[j] << 16);
    }
    __syncthreads();
    stage_b(Wbf, Bs, n0, 192 + c0, w, lrow, lchunk, lane);
    #pragma unroll
    for (int r = 0; r < 4; ++r) {
      int pxb = (pxq0 + 8 * r) * 4;
      #pragma unroll
      for (int j = 0; j < 4; ++j) {
        int px = pxb + j;
        As32[px * 32 + (((kp >> 2) ^ (px & 7)) << 2) + (kp & 3)] = pk[r][j];
      }
    }
    __syncthreads();
    compute_step(As, Bs, acc, wm, wn, l15, quad);
  }

  // epilogue: BN affine + exact GELU; 4 chunks of 32 o-rows; each out row gets
  // one contiguous 512 B store stream (full cache lines, written once).
  float av[4], bv[4];
  #pragma unroll
  for (int ni = 0; ni < 4; ++ni) {
    int o = n0 + wn * 64 + ni * 16 + l15;
    av[ni] = alphaV[o];
    bv[ni] = betaV[o];
  }
  #pragma unroll 1
  for (int oc = 0; oc < 4; ++oc) {
    __syncthreads();
    if (wn == (oc >> 1)) {
      int nbase = (oc & 1) * 2;
      #pragma unroll
      for (int ni2 = 0; ni2 < 2; ++ni2) {
        int ni = nbase + ni2;
        #pragma unroll
        for (int mi = 0; mi < 4; ++mi) {
          floatx4 a = acc[mi][ni];
          float4 g;
          float* gp = &g.x;
          #pragma unroll
          for (int i = 0; i < 4; ++i) {
            float t = a[i] * av[ni] + bv[ni];
            gp[i] = 0.5f * t * (1.0f + erff(t * 0.70710678118654752f));
          }
          *(float4*)&ep[(ni2 * 16 + l15) * 132 + wm * 64 + mi * 16 + quad * 4] = g;
        }
      }
    }
    __syncthreads();
    #pragma unroll
    for (int it = 0; it < 4; ++it) {
      int task = tid + it * 256;
      int r = task >> 5;
      int c4 = task & 31;
      float4 v = *(float4*)&ep[r * 132 + c4 * 4];
      int gm = m0 + c4 * 4;
      int bb = gm / HW_N;
      int pp = gm - bb * HW_N;
      *(float4*)(out + ((size_t)(bb * CO_N + n0 + oc * 32 + r)) * HW_N + pp) = v;
    }
  }
}

extern "C" void kernel_launch(void* const* d_in, const int* in_sizes, int n_in,
                              void* d_out, int out_size, void* d_ws, size_t ws_size,
                              hipStream_t stream) {
  const float* x  = (const float*)d_in[0];
  const float* Wc = (const float*)d_in[1];
  const float* bc = (const float*)d_in[2];
  const float* gm = (const float*)d_in[3];
  const float* bt = (const float*)d_in[4];
  const float* rm = (const float*)d_in[5];
  const float* rv = (const float*)d_in[6];
  float* out = (float*)d_out;

  char* ws = (char*)d_ws;
  size_t offXJ = 0;
  size_t offWb = offXJ + (size_t)B_N * C_N * HW_N * 2;
  size_t offAl = offWb + (size_t)CO_N * K_N * 2;
  u16* XJ = (u16*)(ws + offXJ);
  u16* Wbf = (u16*)(ws + offWb);
  float* alphaV = (float*)(ws + offAl);
  float* betaV = alphaV + CO_N;

  hipLaunchKernelGGL(prep_consts, dim3(576), dim3(256), 0, stream,
                     Wc, bc, gm, bt, rm, rv, Wbf, alphaV, betaV);
  hipLaunchKernelGGL(xj_compute, dim3(B_N * C_N), dim3(256), 0, stream, x, XJ);
  hipLaunchKernelGGL(gemm_fused, dim3(784 * 3), dim3(256), 0, stream,
                     x, XJ, Wbf, alphaV, betaV, out);
}

// Round 2
// 350.550 us; speedup vs baseline: 1.5126x; 1.4796x over previous
//
#include <hip/hip_runtime.h>
#include <cstdint>

#define B_N 32
#define C_N 192
#define W_N 56
#define HW_N 3136
#define CO_N 384
#define K_N 384
#define M_N 100352   // B_N * HW_N

typedef unsigned short u16;
typedef unsigned int u32;
typedef __attribute__((ext_vector_type(8))) short short8;
typedef __attribute__((ext_vector_type(4))) float floatx4;

__device__ __forceinline__ u16 bf16rne(float f) {
  union { float f; u32 u; } v; v.f = f;
  u32 r = (v.u + 0x7FFFu + ((v.u >> 16) & 1u)) >> 16;
  return (u16)r;
}

// ---- direct global->LDS staging (16B/lane). lbase must be wave-uniform. ----
__device__ __forceinline__ void stage16(const void* g, void* lbase, int lane) {
#if __has_builtin(__builtin_amdgcn_global_load_lds)
  __builtin_amdgcn_global_load_lds(
      (const __attribute__((address_space(1))) void*)(uintptr_t)g,
      (__attribute__((address_space(3))) void*)(u32)(uintptr_t)lbase,
      16, 0, 0);
#else
  *(uint4*)((char*)lbase + lane * 16) = *(const uint4*)g;
#endif
}

// ============ K0: fold BN consts, convert W to bf16 ============
__global__ __launch_bounds__(256) void prep_consts(
    const float* __restrict__ Wc, const float* __restrict__ bconv,
    const float* __restrict__ gamma, const float* __restrict__ beta,
    const float* __restrict__ rmean, const float* __restrict__ rvar,
    u16* __restrict__ Wbf, float* __restrict__ alphaV, float* __restrict__ betaV) {
  int idx = blockIdx.x * 256 + threadIdx.x;
  if (idx < CO_N * K_N) Wbf[idx] = bf16rne(Wc[idx]);
  if (idx < CO_N) {
    float s = gamma[idx] * rsqrtf(rvar[idx] + 1e-5f);
    alphaV[idx] = s;
    betaV[idx] = bconv[idx] * s + beta[idx] - rmean[idx] * s;
  }
}

// ============ K1: per-(b,c) plane -> xj (bf16) ============
__global__ __launch_bounds__(256) void xj_compute(const float* __restrict__ x,
                                                  u16* __restrict__ XJ) {
  __shared__ float pl[HW_N];
  __shared__ float rmin1[112], rmin2[112], cmin1[112], cmin2[112];
  __shared__ int rarg[112], carg[112];
  int tid = threadIdx.x;
  size_t base = (size_t)blockIdx.x * HW_N;
  const float4* xp4 = (const float4*)(x + base);
  #pragma unroll 1
  for (int i = tid; i < HW_N / 4; i += 256) ((float4*)pl)[i] = xp4[i];
  __syncthreads();
  if (tid < 112) {            // row-direction structure: per (w, parity)
    int ww = tid >> 1, p = tid & 1;
    float m1 = 3e38f, m2 = 3e38f; int am = -1;
    #pragma unroll
    for (int j = 0; j < 28; ++j) {
      int h = p + 2 * j;
      float v = pl[h * W_N + ww];
      if (v < m1) { m2 = m1; m1 = v; am = h; } else if (v < m2) m2 = v;
    }
    rmin1[tid] = m1; rmin2[tid] = m2; rarg[tid] = am;
  } else if (tid < 224) {     // col-direction structure: per (h, parity)
    int t = tid - 112;
    int hh = t >> 1, p = t & 1;
    float m1 = 3e38f, m2 = 3e38f; int am = -1;
    #pragma unroll
    for (int j = 0; j < 28; ++j) {
      int wv = p + 2 * j;
      float v = pl[hh * W_N + wv];
      if (v < m1) { m2 = m1; m1 = v; am = wv; } else if (v < m2) m2 = v;
    }
    cmin1[t] = m1; cmin2[t] = m2; carg[t] = am;
  }
  __syncthreads();
  u16* op = XJ + base;
  #pragma unroll 1
  for (int i4 = tid; i4 < HW_N / 4; i4 += 256) {
    int idx = i4 * 4;
    int h = idx / W_N;
    int w0 = idx - h * W_N;
    ushort4 r;
    u16* rp = &r.x;
    #pragma unroll
    for (int j = 0; j < 4; ++j) {
      int wv = w0 + j;
      float v = pl[idx + j];
      int rt = (wv << 1) | (h & 1);
      float rm = (rarg[rt] == h) ? rmin2[rt] : rmin1[rt];
      int ct = (h << 1) | (wv & 1);
      float cm = (carg[ct] == wv) ? cmin2[ct] : cmin1[ct];
      float xj = v - fminf(rm, cm);
      rp[j] = bf16rne(fmaxf(xj, 0.0f));
    }
    *(ushort4*)(op + idx) = r;
  }
}

// ============ K2: FUSED all-N GEMM (BM=128, BN=384) + BN + GELU ============
// 512 threads = 8 waves (2m x 4n); per wave 64m x 96n -> acc[4][6].
// As 16KB (bf16, chunk-XOR swizzle g=(px>>1)&7), built in-kernel from x/XJ
// with PIXEL-major lane mapping (16 lanes x 16B = 256B contiguous per channel
// row -> fully-consumed lines, no TA address divergence).
// Bs 48KB: all 384 weight rows per K-step via global_load_lds + XOR swizzle.
// A staged ONCE per m-tile (was 3x); 3x fewer barrier drains; 2 blocks/CU.

__global__ __launch_bounds__(512) void gemm_fused(
    const float* __restrict__ x, const u16* __restrict__ XJ,
    const u16* __restrict__ Wbf,
    const float* __restrict__ alphaV, const float* __restrict__ betaV,
    float* __restrict__ out) {
  __shared__ __align__(16) char smem_raw[65536]; // As 16K + Bs 48K; ep 50.7K
  u16* As = (u16*)smem_raw;
  u32* As32 = (u32*)smem_raw;
  u16* Bs = (u16*)(smem_raw + 16384);
  float* ep = (float*)smem_raw;
  int tid = threadIdx.x;
  int lane = tid & 63;
  int w = tid >> 6;              // 0..7
  int wm = w & 1, wn = w >> 1;   // 2m x 4n
  int l15 = lane & 15, quad = lane >> 4;
  int m0 = blockIdx.x << 7;

  // ---- A-staging map: kp = channel-pair (0..31), pxq = pixel-quad (0..15) ----
  int kp = tid >> 4;
  int pxq = tid & 15;
  u32 offs[2];
  #pragma unroll
  for (int r = 0; r < 2; ++r) {
    int gm = m0 + (pxq + 16 * r) * 4;
    int bb = gm / HW_N;
    int pp = gm - bb * HW_N;
    offs[r] = (u32)bb * (u32)(C_N * HW_N) + (u32)pp;
  }
  // Bs staging map: wave w owns rows w*48..w*48+47 (6 calls x 8 rows)
  int lrow = lane >> 3;
  int lchunk = lane & 7;

  floatx4 acc[4][6];
  #pragma unroll
  for (int i = 0; i < 4; ++i)
    #pragma unroll
    for (int j = 0; j < 6; ++j) acc[i][j] = (floatx4)0.0f;

  // ---- x0 half: k = 0..191 ----
  #pragma unroll 1
  for (int ko = 0; ko < 3; ++ko) {
    int c0 = ko * 64;
    u32 pk[2][4];
    #pragma unroll
    for (int r = 0; r < 2; ++r) {
      const float* a = x + (size_t)offs[r] + (size_t)(c0 + 2 * kp) * HW_N;
      float4 v0 = *(const float4*)a;
      float4 v1 = *(const float4*)(a + HW_N);
      const float* f0 = &v0.x; const float* f1 = &v1.x;
      #pragma unroll
      for (int j = 0; j < 4; ++j)
        pk[r][j] = (u32)bf16rne(f0[j]) | ((u32)bf16rne(f1[j]) << 16);
    }
    __syncthreads();                 // prev compute done reading As/Bs
    #pragma unroll
    for (int c = 0; c < 6; ++c) {    // stage all 384 B-rows for this K-step
      int rowbase = w * 48 + c * 8;
      int row = rowbase + lrow;
      int chunk = lchunk ^ (row & 7);
      stage16(Wbf + (size_t)row * K_N + c0 + chunk * 8, Bs + rowbase * 64, lane);
    }
    #pragma unroll
    for (int r = 0; r < 2; ++r) {
      #pragma unroll
      for (int j = 0; j < 4; ++j) {
        int px = (pxq + 16 * r) * 4 + j;
        As32[px * 32 + (kp & 3) + (((kp >> 2) ^ ((px >> 1) & 7)) << 2)] = pk[r][j];
      }
    }
    __syncthreads();
    #pragma unroll
    for (int h2 = 0; h2 < 2; ++h2) {
      short8 aF[4], bF[6];
      #pragma unroll
      for (int mi = 0; mi < 4; ++mi) {
        int r = wm * 64 + mi * 16 + l15;
        aF[mi] = *(const short8*)(As + r * 64 + (((h2 * 4 + quad) ^ ((r >> 1) & 7)) << 3));
      }
      #pragma unroll
      for (int ni = 0; ni < 6; ++ni) {
        int r = wn * 96 + ni * 16 + l15;
        bF[ni] = *(const short8*)(Bs + r * 64 + (((h2 * 4 + quad) ^ (r & 7)) << 3));
      }
      #pragma unroll
      for (int mi = 0; mi < 4; ++mi)
        #pragma unroll
        for (int ni = 0; ni < 6; ++ni)
          acc[mi][ni] = __builtin_amdgcn_mfma_f32_16x16x32_bf16(
              aF[mi], bF[ni], acc[mi][ni], 0, 0, 0);
    }
  }

  // ---- xj half: k = 192..383 ----
  #pragma unroll 1
  for (int ko = 0; ko < 3; ++ko) {
    int c0 = ko * 64;
    u32 pk[2][4];
    #pragma unroll
    for (int r = 0; r < 2; ++r) {
      const u16* a = XJ + (size_t)offs[r] + (size_t)(c0 + 2 * kp) * HW_N;
      ushort4 v0 = *(const ushort4*)a;
      ushort4 v1 = *(const ushort4*)(a + HW_N);
      const u16* q0 = &v0.x; const u16* q1 = &v1.x;
      #pragma unroll
      for (int j = 0; j < 4; ++j)
        pk[r][j] = (u32)q0[j] | ((u32)q1[j] << 16);
    }
    __syncthreads();
    #pragma unroll
    for (int c = 0; c < 6; ++c) {
      int rowbase = w * 48 + c * 8;
      int row = rowbase + lrow;
      int chunk = lchunk ^ (row & 7);
      stage16(Wbf + (size_t)row * K_N + 192 + c0 + chunk * 8, Bs + rowbase * 64, lane);
    }
    #pragma unroll
    for (int r = 0; r < 2; ++r) {
      #pragma unroll
      for (int j = 0; j < 4; ++j) {
        int px = (pxq + 16 * r) * 4 + j;
        As32[px * 32 + (kp & 3) + (((kp >> 2) ^ ((px >> 1) & 7)) << 2)] = pk[r][j];
      }
    }
    __syncthreads();
    #pragma unroll
    for (int h2 = 0; h2 < 2; ++h2) {
      short8 aF[4], bF[6];
      #pragma unroll
      for (int mi = 0; mi < 4; ++mi) {
        int r = wm * 64 + mi * 16 + l15;
        aF[mi] = *(const short8*)(As + r * 64 + (((h2 * 4 + quad) ^ ((r >> 1) & 7)) << 3));
      }
      #pragma unroll
      for (int ni = 0; ni < 6; ++ni) {
        int r = wn * 96 + ni * 16 + l15;
        bF[ni] = *(const short8*)(Bs + r * 64 + (((h2 * 4 + quad) ^ (r & 7)) << 3));
      }
      #pragma unroll
      for (int mi = 0; mi < 4; ++mi)
        #pragma unroll
        for (int ni = 0; ni < 6; ++ni)
          acc[mi][ni] = __builtin_amdgcn_mfma_f32_16x16x32_bf16(
              aF[mi], bF[ni], acc[mi][ni], 0, 0, 0);
    }
  }

  // ---- epilogue: BN affine + exact GELU; 4 chunks of 96 o-rows ----
  float av[6], bv[6];
  #pragma unroll
  for (int ni = 0; ni < 6; ++ni) {
    int o = wn * 96 + ni * 16 + l15;
    av[ni] = alphaV[o];
    bv[ni] = betaV[o];
  }
  #pragma unroll 1
  for (int oc = 0; oc < 4; ++oc) {
    __syncthreads();
    if (wn == oc) {          // 2 waves (wm 0/1) own this 96-row chunk
      #pragma unroll
      for (int ni = 0; ni < 6; ++ni) {
        #pragma unroll
        for (int mi = 0; mi < 4; ++mi) {
          floatx4 a = acc[mi][ni];
          float4 g;
          float* gp = &g.x;
          #pragma unroll
          for (int i = 0; i < 4; ++i) {
            float t = a[i] * av[ni] + bv[ni];
            gp[i] = 0.5f * t * (1.0f + erff(t * 0.70710678118654752f));
          }
          *(float4*)&ep[(ni * 16 + l15) * 132 + wm * 64 + mi * 16 + quad * 4] = g;
        }
      }
    }
    __syncthreads();
    #pragma unroll
    for (int it = 0; it < 6; ++it) {
      int task = tid + it * 512;    // 3072 tasks = 96 rows x 32 px-quads
      int r = task >> 5;
      int c4 = task & 31;
      float4 v = *(float4*)&ep[r * 132 + c4 * 4];
      int gm = m0 + c4 * 4;
      int bb = gm / HW_N;
      int pp = gm - bb * HW_N;
      *(float4*)(out + ((size_t)(bb * CO_N + oc * 96 + r)) * HW_N + pp) = v;
    }
  }
}

extern "C" void kernel_launch(void* const* d_in, const int* in_sizes, int n_in,
                              void* d_out, int out_size, void* d_ws, size_t ws_size,
                              hipStream_t stream) {
  const float* x  = (const float*)d_in[0];
  const float* Wc = (const float*)d_in[1];
  const float* bc = (const float*)d_in[2];
  const float* gm = (const float*)d_in[3];
  const float* bt = (const float*)d_in[4];
  const float* rm = (const float*)d_in[5];
  const float* rv = (const float*)d_in[6];
  float* out = (float*)d_out;

  char* ws = (char*)d_ws;
  size_t offXJ = 0;
  size_t offWb = offXJ + (size_t)B_N * C_N * HW_N * 2;
  size_t offAl = offWb + (size_t)CO_N * K_N * 2;
  u16* XJ = (u16*)(ws + offXJ);
  u16* Wbf = (u16*)(ws + offWb);
  float* alphaV = (float*)(ws + offAl);
  float* betaV = alphaV + CO_N;

  hipLaunchKernelGGL(prep_consts, dim3(576), dim3(256), 0, stream,
                     Wc, bc, gm, bt, rm, rv, Wbf, alphaV, betaV);
  hipLaunchKernelGGL(xj_compute, dim3(B_N * C_N), dim3(256), 0, stream, x, XJ);
  hipLaunchKernelGGL(gemm_fused, dim3(M_N / 128), dim3(512), 0, stream,
                     x, XJ, Wbf, alphaV, betaV, out);
}